// Round 1
// baseline (2660.301 us; speedup 1.0000x reference)
//
#include <hip/hip_runtime.h>
#include <hip/hip_bf16.h>

// MSDeformAttn fusion, MI355X. Round 1: correct fp32 implementation.
// B=2, T=3, C=256, H=W=64, M=8, P=4, DH=32.
//
// Pipeline:
//   conv1: value = conv3x3(input_flatten (6,256,64,64), w_value) -> pixel-major (6,4096,256)
//   conv2: off   = conv3x3(query (2,768,64,64), w_off)          -> pixel-major (2,4096,192)
//   conv3: attn  = conv3x3(query, w_attn)                        -> pixel-major (2,4096,96)
//   deform: softmax + flow-guided bilinear sampling              -> pixel-major (2,4096,256)
//   conv4: out = conv3x3(deform, w_out)                          -> NCHW (2,256,64,64) = d_out

#define HW_SZ 4096

// Generic 3x3 same-pad conv, H=W=64.
// Tile: 32 out-channels x (8 rows x 16 cols) pixels per 256-thread block.
// grid = (32 spatial tiles, Cout/32, n_images)
// Thread: o0 = tid&15 covers oc {o0, o0+16}; px group p = tid>>4 covers 2x4 px.
template <bool IN_PM, bool OUT_PM>
__global__ __launch_bounds__(256) void conv3x3_kernel(
    const float* __restrict__ in, const float* __restrict__ wgt,
    const float* __restrict__ bias, float* __restrict__ out,
    int Cin, int Cout)
{
    const int n       = blockIdx.z;
    const int oc_base = blockIdx.y * 32;
    const int tile    = blockIdx.x;       // 0..31
    const int ty0     = (tile >> 2) * 8;  // 8 tile-rows
    const int tx0     = (tile & 3) * 16;  // 4 tile-cols

    const int tid = threadIdx.x;
    const int o0  = tid & 15;
    const int p   = tid >> 4;
    const int pr  = (p >> 2) * 2;   // 0,2,4,6
    const int pc  = (p & 3) * 4;    // 0,4,8,12

    __shared__ float s_in[8][10][20];  // [ic][y][x], x padded 18->20
    __shared__ float s_w[8][9][32];    // [ic][tap][oc]

    float acc[2][8];
    #pragma unroll
    for (int k = 0; k < 2; k++) {
        int oc = oc_base + o0 + k * 16;
        float bv = (oc < Cout) ? bias[oc] : 0.f;
        #pragma unroll
        for (int i = 0; i < 8; i++) acc[k][i] = bv;
    }

    for (int ic0 = 0; ic0 < Cin; ic0 += 8) {
        // ---- stage input tile (8 ic x 10 x 18, zero-padded halo) ----
        if (IN_PM) {
            // ic fastest so consecutive lanes read contiguous channels
            for (int idx = tid; idx < 8 * 10 * 18; idx += 256) {
                int ic = idx & 7, pxi = idx >> 3;
                int sy = pxi / 18, sx = pxi % 18;
                int gy = ty0 - 1 + sy, gx = tx0 - 1 + sx;
                float v = 0.f;
                if (gy >= 0 && gy < 64 && gx >= 0 && gx < 64)
                    v = in[(n * HW_SZ + gy * 64 + gx) * Cin + ic0 + ic];
                s_in[ic][sy][sx] = v;
            }
        } else {
            // NCHW: sx fastest so consecutive lanes read contiguous x
            for (int idx = tid; idx < 8 * 10 * 18; idx += 256) {
                int ic = idx / 180, r = idx % 180;
                int sy = r / 18, sx = r % 18;
                int gy = ty0 - 1 + sy, gx = tx0 - 1 + sx;
                float v = 0.f;
                if (gy >= 0 && gy < 64 && gx >= 0 && gx < 64)
                    v = in[((n * Cin + ic0 + ic) * 64 + gy) * 64 + gx];
                s_in[ic][sy][sx] = v;
            }
        }
        // ---- stage weights (32 oc x 8 ic x 9), global layout OIHW ----
        for (int idx = tid; idx < 32 * 8 * 9; idx += 256) {
            int oc = idx / 72, r = idx % 72;
            int ic = r / 9, tap = r % 9;
            int g_oc = oc_base + oc;
            float v = 0.f;
            if (g_oc < Cout) v = wgt[(g_oc * Cin + ic0 + ic) * 9 + tap];
            s_w[ic][tap][oc] = v;
        }
        __syncthreads();

        for (int ic = 0; ic < 8; ic++) {
            // register-cache the 4x6 input patch this thread needs
            float patch[4][6];
            #pragma unroll
            for (int r = 0; r < 4; r++)
                #pragma unroll
                for (int c = 0; c < 6; c++)
                    patch[r][c] = s_in[ic][pr + r][pc + c];
            #pragma unroll
            for (int ky = 0; ky < 3; ky++)
                #pragma unroll
                for (int kx = 0; kx < 3; kx++) {
                    float w0 = s_w[ic][ky * 3 + kx][o0];
                    float w1 = s_w[ic][ky * 3 + kx][o0 + 16];
                    #pragma unroll
                    for (int i = 0; i < 2; i++)
                        #pragma unroll
                        for (int j = 0; j < 4; j++) {
                            float v = patch[i + ky][j + kx];
                            acc[0][i * 4 + j] += w0 * v;
                            acc[1][i * 4 + j] += w1 * v;
                        }
                }
        }
        __syncthreads();
    }

    #pragma unroll
    for (int k = 0; k < 2; k++) {
        int oc = oc_base + o0 + k * 16;
        if (oc >= Cout) continue;
        #pragma unroll
        for (int i = 0; i < 2; i++)
            #pragma unroll
            for (int j = 0; j < 4; j++) {
                int y = ty0 + pr + i, x = tx0 + pc + j;
                if (OUT_PM) out[(n * HW_SZ + y * 64 + x) * Cout + oc] = acc[k][i * 4 + j];
                else        out[((n * Cout + oc) * 64 + y) * 64 + x] = acc[k][i * 4 + j];
            }
    }
}

// Deform sampling: thread = (b, q, m, d). value_t pixel-major (b*3+t, pix, 256).
__global__ __launch_bounds__(256) void deform_kernel(
    const float* __restrict__ value_t,  // (6, 4096, 256)
    const float* __restrict__ off_t,    // (2, 4096, 192) ch = m*24 + t*8 + p*2 + comp
    const float* __restrict__ attn_t,   // (2, 4096, 96)  ch = m*12 + t*4 + p
    const float* __restrict__ refp,     // (2, 4096, 3, 2)
    const float* __restrict__ flow_fwd, // (2, 2, 2, 64, 64)
    const float* __restrict__ flow_bwd, // (2, 2, 2, 64, 64)
    float* __restrict__ out_t)          // (2, 4096, 256)
{
    int gid = blockIdx.x * 256 + threadIdx.x;
    int d = gid & 31;
    int m = (gid >> 5) & 7;
    int q = (gid >> 8) & 4095;
    int b = gid >> 20;

    // softmax over T*P = 12 logits (reads broadcast across the 32 d-lanes)
    const float* al = attn_t + (b * HW_SZ + q) * 96 + m * 12;
    float lg[12];
    float mx = -1e30f;
    #pragma unroll
    for (int i = 0; i < 12; i++) { lg[i] = al[i]; mx = fmaxf(mx, lg[i]); }
    float s = 0.f;
    #pragma unroll
    for (int i = 0; i < 12; i++) { lg[i] = __expf(lg[i] - mx); s += lg[i]; }
    float inv = 1.f / s;

    const float* op = off_t + (b * HW_SZ + q) * 192 + m * 24;
    const float* rp = refp + (b * HW_SZ + q) * 6;

    float acc = 0.f;
    #pragma unroll
    for (int t = 0; t < 3; t++) {
        float fx = 0.f, fy = 0.f;
        if (t == 0) {  // backward flow, [b][0][comp]
            fx = flow_bwd[((b * 2 + 0) * 2 + 0) * HW_SZ + q];
            fy = flow_bwd[((b * 2 + 0) * 2 + 1) * HW_SZ + q];
        } else if (t == 2) {  // forward flow, [b][1][comp]
            fx = flow_fwd[((b * 2 + 1) * 2 + 0) * HW_SZ + q];
            fy = flow_fwd[((b * 2 + 1) * 2 + 1) * HW_SZ + q];
        }
        float rx = rp[t * 2 + 0], ry = rp[t * 2 + 1];
        const float* vbase = value_t + (b * 3 + t) * (HW_SZ * 256) + m * 32 + d;
        #pragma unroll
        for (int pp = 0; pp < 4; pp++) {
            float ox = op[t * 8 + pp * 2 + 0] + fx;
            float oy = op[t * 8 + pp * 2 + 1] + fy;
            float aw = lg[t * 4 + pp] * inv;
            // x = loc_x*W - 0.5 = rx*64 + ox - 0.5 (align_corners=False)
            float x = rx * 64.f + ox - 0.5f;
            float y = ry * 64.f + oy - 0.5f;
            float x0f = floorf(x), y0f = floorf(y);
            float wx = x - x0f, wy = y - y0f;
            int x0 = (int)x0f, y0 = (int)y0f;
            int x1 = x0 + 1, y1 = y0 + 1;
            bool vx0 = (x0 >= 0) & (x0 < 64), vx1 = (x1 >= 0) & (x1 < 64);
            bool vy0 = (y0 >= 0) & (y0 < 64), vy1 = (y1 >= 0) & (y1 < 64);
            int cx0 = min(max(x0, 0), 63), cx1 = min(max(x1, 0), 63);
            int cy0 = min(max(y0, 0), 63), cy1 = min(max(y1, 0), 63);
            float w00 = (1.f - wx) * (1.f - wy) * ((vx0 & vy0) ? 1.f : 0.f);
            float w10 = wx * (1.f - wy) * ((vx1 & vy0) ? 1.f : 0.f);
            float w01 = (1.f - wx) * wy * ((vx0 & vy1) ? 1.f : 0.f);
            float w11 = wx * wy * ((vx1 & vy1) ? 1.f : 0.f);
            float v00 = vbase[(cy0 * 64 + cx0) * 256];
            float v10 = vbase[(cy0 * 64 + cx1) * 256];
            float v01 = vbase[(cy1 * 64 + cx0) * 256];
            float v11 = vbase[(cy1 * 64 + cx1) * 256];
            acc += aw * (w00 * v00 + w10 * v10 + w01 * v01 + w11 * v11);
        }
    }
    out_t[(b * HW_SZ + q) * 256 + m * 32 + d] = acc;
}

extern "C" void kernel_launch(void* const* d_in, const int* in_sizes, int n_in,
                              void* d_out, int out_size, void* d_ws, size_t ws_size,
                              hipStream_t stream) {
    const float* query   = (const float*)d_in[0];   // (2,3,256,64,64) = (2,768,64,64)
    const float* refp    = (const float*)d_in[1];   // (2,4096,3,2)
    const float* inflat  = (const float*)d_in[2];   // (2,3,256,64,64) = (6,256,64,64)
    // d_in[3..5]: spatial shapes / level start / padding mask (all-zero) — unused
    const float* flowf   = (const float*)d_in[6];   // (2,2,2,64,64)
    const float* flowb   = (const float*)d_in[7];   // (2,2,2,64,64)
    const float* w_value = (const float*)d_in[8];
    const float* b_value = (const float*)d_in[9];
    const float* w_off   = (const float*)d_in[10];
    const float* b_off   = (const float*)d_in[11];
    const float* w_attn  = (const float*)d_in[12];
    const float* b_attn  = (const float*)d_in[13];
    const float* w_out   = (const float*)d_in[14];
    const float* b_out   = (const float*)d_in[15];
    float* out = (float*)d_out;

    float* ws      = (float*)d_ws;
    float* value_t = ws;                               // 6*4096*256 = 6,291,456
    float* off_t   = value_t + 6 * HW_SZ * 256;        // 2*4096*192 = 1,572,864
    float* attn_t  = off_t + 2 * HW_SZ * 192;          // 2*4096*96  =   786,432
    float* dout_t  = attn_t + 2 * HW_SZ * 96;          // 2*4096*256 = 2,097,152

    dim3 blk(256);
    // value conv: 6 images, 256->256, NCHW in, pixel-major out
    conv3x3_kernel<false, true><<<dim3(32, 8, 6), blk, 0, stream>>>(
        inflat, w_value, b_value, value_t, 256, 256);
    // offset conv: 2 images, 768->192
    conv3x3_kernel<false, true><<<dim3(32, 6, 2), blk, 0, stream>>>(
        query, w_off, b_off, off_t, 768, 192);
    // attention conv: 2 images, 768->96
    conv3x3_kernel<false, true><<<dim3(32, 3, 2), blk, 0, stream>>>(
        query, w_attn, b_attn, attn_t, 768, 96);
    // deform sampling: 2*4096*8*32 threads
    deform_kernel<<<dim3(8192), blk, 0, stream>>>(
        value_t, off_t, attn_t, refp, flowf, flowb, dout_t);
    // output conv: 2 images, 256->256, pixel-major in, NCHW out -> d_out
    conv3x3_kernel<true, false><<<dim3(32, 8, 2), blk, 0, stream>>>(
        dout_t, w_out, b_out, out, 256, 256);
}

// Round 2
// 628.043 us; speedup vs baseline: 4.2359x; 4.2359x over previous
//
#include <hip/hip_runtime.h>

// MSDeformAttn fusion, MI355X. Round 2: bf16 MFMA implicit-GEMM convs.
// B=2, T=3, C=256, H=W=64, M=8, P=4, DH=32.

#define HW_SZ 4096

typedef __attribute__((ext_vector_type(8))) short short8;
typedef __attribute__((ext_vector_type(4))) float f32x4;

__device__ __forceinline__ unsigned short f2bf(float f) {
    union { float f; unsigned u; } v; v.f = f;
    unsigned u = v.u;
    unsigned r = (u + 0x7FFFu + ((u >> 16) & 1u)) >> 16;
    return (unsigned short)r;
}
__device__ __forceinline__ float bf2f(unsigned short h) {
    union { unsigned u; float f; } v; v.u = ((unsigned)h) << 16;
    return v.f;
}

// ---------------- weight repack: OIHW fp32 -> [tap][ob][kb][lane][8] bf16 ----
// oc = ob*16 + (lane&15), ic = kb*32 + (lane>>4)*8 + j. oc >= Cout -> 0.
// Two sources concatenated at `split` (w1 starts at oc==split).
__global__ __launch_bounds__(256) void repack_w(
    const float* __restrict__ w0, const float* __restrict__ w1,
    int split, int Cout, int Cin, int OBp, unsigned short* __restrict__ out,
    int ngroups)
{
    int g = blockIdx.x * 256 + threadIdx.x;
    if (g >= ngroups) return;
    int lane = g & 63;
    int rest = g >> 6;
    int KB = Cin >> 5;
    int kb = rest % KB; int rest2 = rest / KB;
    int ob = rest2 % OBp; int tap = rest2 / OBp;
    int oc = ob * 16 + (lane & 15);
    int ic0 = kb * 32 + (lane >> 4) * 8;
    unsigned v[4];
    #pragma unroll
    for (int j = 0; j < 4; ++j) {
        unsigned lo = 0, hi = 0;
        int ic = ic0 + 2 * j;
        if (oc < split) {
            lo = f2bf(w0[((size_t)oc * Cin + ic) * 9 + tap]);
            hi = f2bf(w0[((size_t)oc * Cin + ic + 1) * 9 + tap]);
        } else if (oc < Cout) {
            lo = f2bf(w1[((size_t)(oc - split) * Cin + ic) * 9 + tap]);
            hi = f2bf(w1[((size_t)(oc - split) * Cin + ic + 1) * 9 + tap]);
        }
        v[j] = lo | (hi << 16);
    }
    uint4 o; o.x = v[0]; o.y = v[1]; o.z = v[2]; o.w = v[3];
    *(uint4*)(out + (size_t)g * 8) = o;
}

__global__ void build_qbias(const float* __restrict__ boff,
                            const float* __restrict__ battn,
                            float* __restrict__ qb)
{
    int i = blockIdx.x * 128 + threadIdx.x;
    if (i >= 384) return;
    float v = 0.f;
    if (i < 192) v = boff[i]; else if (i < 288) v = battn[i - 192];
    qb[i] = v;
}

// ---------------- NCHW fp32 -> pixel-major bf16 transpose ----------------
// grid (64 rows, Cin/32, imgs), block 256.
__global__ __launch_bounds__(256) void nchw_to_pm(
    const float* __restrict__ in, unsigned short* __restrict__ out, int Cin)
{
    int y = blockIdx.x, kb = blockIdx.y, img = blockIdx.z;
    __shared__ float s[32][65];
    int t = threadIdx.x;
    int x = t & 63, ic4 = t >> 6;
    const float* ip = in + ((size_t)img * Cin + kb * 32) * HW_SZ + y * 64;
    #pragma unroll
    for (int i = 0; i < 8; ++i) {
        int icl = ic4 * 8 + i;
        s[icl][x] = ip[(size_t)icl * HW_SZ + x];
    }
    __syncthreads();
    int p = t >> 2, h = t & 3;
    unsigned v[4];
    #pragma unroll
    for (int j = 0; j < 4; ++j) {
        unsigned lo = f2bf(s[h * 8 + 2 * j][p]);
        unsigned hi = f2bf(s[h * 8 + 2 * j + 1][p]);
        v[j] = lo | (hi << 16);
    }
    uint4 o; o.x = v[0]; o.y = v[1]; o.z = v[2]; o.w = v[3];
    *(uint4*)(out + ((size_t)img * HW_SZ + y * 64 + p) * Cin + kb * 32 + h * 8) = o;
}

// ---------------- MFMA implicit-GEMM conv3x3 ----------------
// in_pm:  [img][4096][Cin] bf16 (pixel-major)
// wpk:    [9][OBp][KB][64][8] bf16 fragment-packed
// Block: 128 thr = 2 waves; wave = 64 oc x 64 px (one image row y0).
// grid = (64 rows, OBp*16/128 blocks, imgs)
// OutMode: 0 = pixel-major bf16, 1 = pixel-major f32, 2 = NCHW f32
template <int OutMode>
__global__ __launch_bounds__(128) void conv_mfma(
    const unsigned short* __restrict__ in_pm,
    const unsigned short* __restrict__ wpk,
    const float* __restrict__ bias, void* __restrict__ outp,
    int Cin, int Cout, int OBp)
{
    const int y0 = blockIdx.x;
    const int mb = blockIdx.y;
    const int img = blockIdx.z;
    const int tid = threadIdx.x;
    const int wv = tid >> 6;
    const int lane = tid & 63;
    const int l16 = lane & 15, lg = lane >> 4;
    const int KB = Cin >> 5;

    // unit = 16B (8 ic) at (icg, rr, cc): index = icg*198 + rr*66 + cc
    __shared__ __align__(16) unsigned short s_in[4 * 198 * 8];  // 12672 B

    f32x4 acc[4][4];
    #pragma unroll
    for (int a = 0; a < 4; ++a)
        #pragma unroll
        for (int b = 0; b < 4; ++b)
            acc[a][b] = (f32x4){0.f, 0.f, 0.f, 0.f};

    const unsigned short* gin = in_pm + (size_t)img * HW_SZ * Cin;

    for (int kb = 0; kb < KB; ++kb) {
        __syncthreads();
        // stage 3 rows x 66 cols x 32 ic (zero halo)
        for (int u = tid; u < 792; u += 128) {
            int icg = u & 3, pxu = u >> 2;
            int cc = pxu % 66, rr = pxu / 66;
            int gy = y0 - 1 + rr, gx = cc - 1;
            uint4 val; val.x = val.y = val.z = val.w = 0u;
            if ((unsigned)gy < 64u && (unsigned)gx < 64u)
                val = *(const uint4*)(gin + ((size_t)(gy * 64 + gx)) * Cin + kb * 32 + icg * 8);
            *(uint4*)(s_in + ((size_t)icg * 198 + pxu) * 8) = val;
        }
        __syncthreads();

        #pragma unroll
        for (int tap = 0; tap < 9; ++tap) {
            const int ky = tap / 3, kx = tap % 3;
            short8 bfr[4], afr[4];
            #pragma unroll
            for (int pt = 0; pt < 4; ++pt)
                bfr[pt] = *(const short8*)(s_in + (lg * 198 + ky * 66 + kx + pt * 16 + l16) * 8);
            #pragma unroll
            for (int ob = 0; ob < 4; ++ob) {
                int obg = mb * 8 + wv * 4 + ob;
                afr[ob] = *(const short8*)(wpk + ((((size_t)tap * OBp + obg) * KB + kb) * 64 + lane) * 8);
            }
            #pragma unroll
            for (int ob = 0; ob < 4; ++ob)
                #pragma unroll
                for (int pt = 0; pt < 4; ++pt)
                    acc[ob][pt] = __builtin_amdgcn_mfma_f32_16x16x32_bf16(
                        afr[ob], bfr[pt], acc[ob][pt], 0, 0, 0);
        }
    }

    __syncthreads();
    if (OutMode == 2) {
        float* outf = (float*)outp;
        #pragma unroll
        for (int ob = 0; ob < 4; ++ob) {
            int obg = mb * 8 + wv * 4 + ob;
            #pragma unroll
            for (int r = 0; r < 4; ++r) {
                int oc = obg * 16 + lg * 4 + r;
                float bv = bias[oc];
                #pragma unroll
                for (int pt = 0; pt < 4; ++pt) {
                    int x = pt * 16 + l16;
                    outf[(((size_t)img * Cout + oc) << 12) + (y0 << 6) + x] = acc[ob][pt][r] + bv;
                }
            }
        }
    } else {
        float* s_ep = (float*)s_in + wv * (64 * 17);
        for (int ob = 0; ob < 4; ++ob) {
            int obg = mb * 8 + wv * 4 + ob;
            #pragma unroll
            for (int r = 0; r < 4; ++r) {
                float bv = bias[obg * 16 + lg * 4 + r];
                #pragma unroll
                for (int pt = 0; pt < 4; ++pt)
                    s_ep[(pt * 16 + l16) * 17 + lg * 4 + r] = acc[ob][pt][r] + bv;
            }
            __syncthreads();
            if (obg * 16 < Cout) {
                size_t pxg = (size_t)img * HW_SZ + y0 * 64 + lane;
                if (OutMode == 1) {
                    float* op = (float*)outp + pxg * Cout + obg * 16;
                    #pragma unroll
                    for (int jj = 0; jj < 4; ++jj) {
                        float4 t4;
                        t4.x = s_ep[lane * 17 + jj * 4 + 0];
                        t4.y = s_ep[lane * 17 + jj * 4 + 1];
                        t4.z = s_ep[lane * 17 + jj * 4 + 2];
                        t4.w = s_ep[lane * 17 + jj * 4 + 3];
                        *(float4*)(op + jj * 4) = t4;
                    }
                } else {
                    unsigned short* op = (unsigned short*)outp + pxg * Cout + obg * 16;
                    unsigned v[8];
                    #pragma unroll
                    for (int j = 0; j < 8; ++j) {
                        unsigned lo = f2bf(s_ep[lane * 17 + 2 * j]);
                        unsigned hi = f2bf(s_ep[lane * 17 + 2 * j + 1]);
                        v[j] = lo | (hi << 16);
                    }
                    uint4 o0; o0.x = v[0]; o0.y = v[1]; o0.z = v[2]; o0.w = v[3];
                    uint4 o1; o1.x = v[4]; o1.y = v[5]; o1.z = v[6]; o1.w = v[7];
                    *(uint4*)(op) = o0;
                    *(uint4*)(op + 8) = o1;
                }
            }
            __syncthreads();
        }
    }
}

// ---------------- deform sampling ----------------
// value_bf: (6,4096,256) bf16 pixel-major; qout: (2,4096,288) f32 (off 0..191, attn 192..287)
__global__ __launch_bounds__(256) void deform_kernel(
    const unsigned short* __restrict__ value_bf,
    const float* __restrict__ qout,
    const float* __restrict__ refp,
    const float* __restrict__ flow_fwd,
    const float* __restrict__ flow_bwd,
    unsigned short* __restrict__ dout)
{
    int gid = blockIdx.x * 256 + threadIdx.x;
    int d = gid & 31;
    int m = (gid >> 5) & 7;
    int q = (gid >> 8) & 4095;
    int b = gid >> 20;

    const float* qbase = qout + ((size_t)b * HW_SZ + q) * 288;
    const float* al = qbase + 192 + m * 12;
    float lg[12];
    float mx = -1e30f;
    #pragma unroll
    for (int i = 0; i < 12; i++) { lg[i] = al[i]; mx = fmaxf(mx, lg[i]); }
    float s = 0.f;
    #pragma unroll
    for (int i = 0; i < 12; i++) { lg[i] = __expf(lg[i] - mx); s += lg[i]; }
    float inv = 1.f / s;

    const float* op = qbase + m * 24;
    const float* rp = refp + ((size_t)b * HW_SZ + q) * 6;

    float acc = 0.f;
    #pragma unroll
    for (int t = 0; t < 3; t++) {
        float fx = 0.f, fy = 0.f;
        if (t == 0) {
            fx = flow_bwd[((b * 2 + 0) * 2 + 0) * HW_SZ + q];
            fy = flow_bwd[((b * 2 + 0) * 2 + 1) * HW_SZ + q];
        } else if (t == 2) {
            fx = flow_fwd[((b * 2 + 1) * 2 + 0) * HW_SZ + q];
            fy = flow_fwd[((b * 2 + 1) * 2 + 1) * HW_SZ + q];
        }
        float rx = rp[t * 2 + 0], ry = rp[t * 2 + 1];
        const unsigned short* vbase = value_bf + (size_t)(b * 3 + t) * (HW_SZ * 256) + m * 32 + d;
        #pragma unroll
        for (int pp = 0; pp < 4; pp++) {
            float ox = op[t * 8 + pp * 2 + 0] + fx;
            float oy = op[t * 8 + pp * 2 + 1] + fy;
            float aw = lg[t * 4 + pp] * inv;
            float x = rx * 64.f + ox - 0.5f;
            float y = ry * 64.f + oy - 0.5f;
            float x0f = floorf(x), y0f = floorf(y);
            float wx = x - x0f, wy = y - y0f;
            int x0 = (int)x0f, y0 = (int)y0f;
            int x1 = x0 + 1, y1 = y0 + 1;
            bool vx0 = (x0 >= 0) & (x0 < 64), vx1 = (x1 >= 0) & (x1 < 64);
            bool vy0 = (y0 >= 0) & (y0 < 64), vy1 = (y1 >= 0) & (y1 < 64);
            int cx0 = min(max(x0, 0), 63), cx1 = min(max(x1, 0), 63);
            int cy0 = min(max(y0, 0), 63), cy1 = min(max(y1, 0), 63);
            float w00 = (1.f - wx) * (1.f - wy) * ((vx0 & vy0) ? 1.f : 0.f);
            float w10 = wx * (1.f - wy) * ((vx1 & vy0) ? 1.f : 0.f);
            float w01 = (1.f - wx) * wy * ((vx0 & vy1) ? 1.f : 0.f);
            float w11 = wx * wy * ((vx1 & vy1) ? 1.f : 0.f);
            float v00 = bf2f(vbase[(cy0 * 64 + cx0) * 256]);
            float v10 = bf2f(vbase[(cy0 * 64 + cx1) * 256]);
            float v01 = bf2f(vbase[(cy1 * 64 + cx0) * 256]);
            float v11 = bf2f(vbase[(cy1 * 64 + cx1) * 256]);
            acc += aw * (w00 * v00 + w10 * v10 + w01 * v01 + w11 * v11);
        }
    }
    dout[((size_t)b * HW_SZ + q) * 256 + m * 32 + d] = f2bf(acc);
}

extern "C" void kernel_launch(void* const* d_in, const int* in_sizes, int n_in,
                              void* d_out, int out_size, void* d_ws, size_t ws_size,
                              hipStream_t stream) {
    const float* query   = (const float*)d_in[0];
    const float* refp    = (const float*)d_in[1];
    const float* inflat  = (const float*)d_in[2];
    const float* flowf   = (const float*)d_in[6];
    const float* flowb   = (const float*)d_in[7];
    const float* w_value = (const float*)d_in[8];
    const float* b_value = (const float*)d_in[9];
    const float* w_off   = (const float*)d_in[10];
    const float* b_off   = (const float*)d_in[11];
    const float* w_attn  = (const float*)d_in[12];
    const float* b_attn  = (const float*)d_in[13];
    const float* w_out   = (const float*)d_in[14];
    const float* b_out   = (const float*)d_in[15];

    char* ws = (char*)d_ws;
    // workspace layout (bytes)
    unsigned short* wpk_v = (unsigned short*)(ws);                       // 1,179,648
    unsigned short* wpk_q = (unsigned short*)(ws + 1179648);             // 5,308,416
    unsigned short* wpk_o = (unsigned short*)(ws + 6488064);             // 1,179,648
    float*          qbias = (float*)(ws + 7667712);                     // 1,536 (pad 2048)
    unsigned short* value_bf = (unsigned short*)(ws + 7669760);          // 12,582,912
    unsigned short* qin_bf   = (unsigned short*)(ws + 20252672);         // 12,582,912
    // REGION A (union): vin_bf (12.58MB) then reused as qout(9.44MB)+dout(4.19MB)
    unsigned short* vin_bf   = (unsigned short*)(ws + 32835584);
    float*          qout     = (float*)(ws + 32835584);
    unsigned short* dout_bf  = (unsigned short*)(ws + 32835584 + 9437184);
    // total = 46,467,072 bytes

    // 1) repack weights + qbias
    repack_w<<<dim3(288), dim3(256), 0, stream>>>(w_value, w_value, 256, 256, 256, 16, wpk_v, 73728);
    repack_w<<<dim3(1296), dim3(256), 0, stream>>>(w_off, w_attn, 192, 288, 768, 24, wpk_q, 331776);
    repack_w<<<dim3(288), dim3(256), 0, stream>>>(w_out, w_out, 256, 256, 256, 16, wpk_o, 73728);
    build_qbias<<<dim3(3), dim3(128), 0, stream>>>(b_off, b_attn, qbias);

    // 2) transpose-convert inputs to pixel-major bf16
    nchw_to_pm<<<dim3(64, 8, 6), dim3(256), 0, stream>>>(inflat, vin_bf, 256);
    nchw_to_pm<<<dim3(64, 24, 2), dim3(256), 0, stream>>>(query, qin_bf, 768);

    // 3) value conv: 6 imgs, 256->256, out pixel-major bf16
    conv_mfma<0><<<dim3(64, 2, 6), dim3(128), 0, stream>>>(
        vin_bf, wpk_v, b_value, (void*)value_bf, 256, 256, 16);

    // 4) off+attn merged conv: 2 imgs, 768->288, out pixel-major f32
    conv_mfma<1><<<dim3(64, 3, 2), dim3(128), 0, stream>>>(
        qin_bf, wpk_q, qbias, (void*)qout, 768, 288, 24);

    // 5) deform sampling -> pixel-major bf16
    deform_kernel<<<dim3(8192), dim3(256), 0, stream>>>(
        value_bf, qout, refp, flowf, flowb, dout_bf);

    // 6) output conv: 2 imgs, 256->256, NCHW f32 -> d_out
    conv_mfma<2><<<dim3(64, 2, 2), dim3(128), 0, stream>>>(
        dout_bf, wpk_o, b_out, d_out, 256, 256, 16);
}

// Round 3
// 417.420 us; speedup vs baseline: 6.3732x; 1.5046x over previous
//
#include <hip/hip_runtime.h>

// MSDeformAttn fusion, MI355X. Round 3: pipelined MFMA convs
// (global_load_lds double-buffer, 128x128 tiles, merged value+qconv launch).
// B=2, T=3, C=256, H=W=64, M=8, P=4, DH=32.

#define HW_SZ 4096

typedef __attribute__((ext_vector_type(8))) short short8;
typedef __attribute__((ext_vector_type(4))) float f32x4;

__device__ __forceinline__ unsigned short f2bf(float f) {
    union { float f; unsigned u; } v; v.f = f;
    unsigned u = v.u;
    unsigned r = (u + 0x7FFFu + ((u >> 16) & 1u)) >> 16;
    return (unsigned short)r;
}
__device__ __forceinline__ float bf2f(unsigned short h) {
    union { unsigned u; float f; } v; v.u = ((unsigned)h) << 16;
    return v.f;
}

// async global(16B/lane) -> LDS (wave-uniform base + lane*16)
__device__ __forceinline__ void gld16(const void* g, void* l) {
    __builtin_amdgcn_global_load_lds(
        (const __attribute__((address_space(1))) unsigned*)g,
        (__attribute__((address_space(3))) unsigned*)l, 16, 0, 0);
}

// ---------------- weight repack: OIHW fp32 -> [tap][ob][kb][lane][8] bf16 ----
__global__ __launch_bounds__(256) void repack_w(
    const float* __restrict__ w0, const float* __restrict__ w1,
    int split, int Cout, int Cin, int OBp, unsigned short* __restrict__ out,
    int ngroups)
{
    int g = blockIdx.x * 256 + threadIdx.x;
    if (g >= ngroups) return;
    int lane = g & 63;
    int rest = g >> 6;
    int KB = Cin >> 5;
    int kb = rest % KB; int rest2 = rest / KB;
    int ob = rest2 % OBp; int tap = rest2 / OBp;
    int oc = ob * 16 + (lane & 15);
    int ic0 = kb * 32 + (lane >> 4) * 8;
    unsigned v[4];
    #pragma unroll
    for (int j = 0; j < 4; ++j) {
        unsigned lo = 0, hi = 0;
        int ic = ic0 + 2 * j;
        if (oc < split) {
            lo = f2bf(w0[((size_t)oc * Cin + ic) * 9 + tap]);
            hi = f2bf(w0[((size_t)oc * Cin + ic + 1) * 9 + tap]);
        } else if (oc < Cout) {
            lo = f2bf(w1[((size_t)(oc - split) * Cin + ic) * 9 + tap]);
            hi = f2bf(w1[((size_t)(oc - split) * Cin + ic + 1) * 9 + tap]);
        }
        v[j] = lo | (hi << 16);
    }
    uint4 o; o.x = v[0]; o.y = v[1]; o.z = v[2]; o.w = v[3];
    *(uint4*)(out + (size_t)g * 8) = o;
}

__global__ void build_qbias(const float* __restrict__ boff,
                            const float* __restrict__ battn,
                            float* __restrict__ qb, float* __restrict__ zb)
{
    int i = blockIdx.x * 128 + threadIdx.x;
    if (i < 16) zb[i] = 0.f;
    if (i >= 384) return;
    float v = 0.f;
    if (i < 192) v = boff[i]; else if (i < 288) v = battn[i - 192];
    qb[i] = v;
}

// ---------------- NCHW fp32 -> pixel-major bf16 transpose ----------------
__global__ __launch_bounds__(256) void nchw_to_pm(
    const float* __restrict__ in, unsigned short* __restrict__ out, int Cin)
{
    int y = blockIdx.x, kb = blockIdx.y, img = blockIdx.z;
    __shared__ float s[32][65];
    int t = threadIdx.x;
    int x = t & 63, ic4 = t >> 6;
    const float* ip = in + ((size_t)img * Cin + kb * 32) * HW_SZ + y * 64;
    #pragma unroll
    for (int i = 0; i < 8; ++i) {
        int icl = ic4 * 8 + i;
        s[icl][x] = ip[(size_t)icl * HW_SZ + x];
    }
    __syncthreads();
    int p = t >> 2, h = t & 3;
    unsigned v[4];
    #pragma unroll
    for (int j = 0; j < 4; ++j) {
        unsigned lo = f2bf(s[h * 8 + 2 * j][p]);
        unsigned hi = f2bf(s[h * 8 + 2 * j + 1][p]);
        v[j] = lo | (hi << 16);
    }
    uint4 o; o.x = v[0]; o.y = v[1]; o.z = v[2]; o.w = v[3];
    *(uint4*)(out + ((size_t)img * HW_SZ + y * 64 + p) * Cin + kb * 32 + h * 8) = o;
}

// ---------------- pipelined MFMA conv core ----------------
// Block: 256 thr = 4 waves. Tile: 128 oc x 128 px (2 output rows).
// wave: ocw = wv&1 (oc half), yr = wv>>1 (row). Wave tile 64oc x 64px.
// LDS: 2 buffers x [4 rows][4 icg][66 cols] 16B units (8448 shorts each).
// Staging: wave wv stages input row y0-1+wv via global_load_lds (dest contiguous).
// outmode: 0 = pixel-major bf16, 1 = pixel-major f32, 2 = NCHW f32.
__device__ __forceinline__ void conv_core(
    const unsigned short* __restrict__ gin,   // per-image pixel-major base
    const unsigned short* __restrict__ wpk,   // [9][OBp][KB][64][8]
    const float* __restrict__ bias,
    const unsigned short* __restrict__ zbuf,
    void* __restrict__ outp,
    int Cin, int KB, int OBp, int Cout, int mb, int y0, int outmode, int img,
    unsigned short* sbuf)
{
    const int tid = threadIdx.x;
    const int wv = tid >> 6, lane = tid & 63;
    const int l16 = lane & 15, lg = lane >> 4;
    const int ocw = wv & 1, yr = wv >> 1;
    const int gy = y0 - 1 + wv;

    f32x4 acc[4][4];
    #pragma unroll
    for (int a = 0; a < 4; ++a)
        #pragma unroll
        for (int b = 0; b < 4; ++b)
            acc[a][b] = (f32x4){0.f, 0.f, 0.f, 0.f};

    auto stage = [&](int kb, unsigned short* sb) {
        #pragma unroll
        for (int i = 0; i < 5; ++i) {
            int r = i * 64 + lane;
            if (r < 264) {
                int icg = r / 66;
                int col = r - icg * 66;
                int gx = col - 1;
                const unsigned short* src =
                    ((unsigned)gy < 64u && (unsigned)gx < 64u)
                        ? (gin + (size_t)(gy * 64 + gx) * Cin + kb * 32 + icg * 8)
                        : zbuf;
                gld16(src, sb + (size_t)(wv * 264 + i * 64) * 8);
            }
        }
    };

    stage(0, sbuf);
    for (int kb = 0; kb < KB; ++kb) {
        __syncthreads();   // drains prefetch vmcnt; buffer kb ready for all waves
        if (kb + 1 < KB) stage(kb + 1, sbuf + ((kb + 1) & 1) * 8448);
        const unsigned short* cb = sbuf + (kb & 1) * 8448;
        #pragma unroll
        for (int tap = 0; tap < 9; ++tap) {
            const int ky = tap / 3, kx = tap % 3;
            short8 afr[4], bfr[4];
            const unsigned short* wp =
                wpk + (((size_t)tap * OBp + (mb * 8 + ocw * 4)) * KB + kb) * 512;
            #pragma unroll
            for (int ob = 0; ob < 4; ++ob)
                afr[ob] = *(const short8*)(wp + (size_t)ob * KB * 512 + lane * 8);
            #pragma unroll
            for (int pt = 0; pt < 4; ++pt)
                bfr[pt] = *(const short8*)(cb + ((yr + ky) * 264 + lg * 66 + kx + pt * 16 + l16) * 8);
            #pragma unroll
            for (int ob = 0; ob < 4; ++ob)
                #pragma unroll
                for (int pt = 0; pt < 4; ++pt)
                    acc[ob][pt] = __builtin_amdgcn_mfma_f32_16x16x32_bf16(
                        afr[ob], bfr[pt], acc[ob][pt], 0, 0, 0);
        }
    }
    __syncthreads();  // all LDS reads done; reuse sbuf for epilogue

    if (outmode == 2) {
        float* outf = (float*)outp + (size_t)img * Cout * HW_SZ + (size_t)(y0 + yr) * 64;
        #pragma unroll
        for (int ob = 0; ob < 4; ++ob) {
            int obg = mb * 8 + ocw * 4 + ob;
            #pragma unroll
            for (int r = 0; r < 4; ++r) {
                int oc = obg * 16 + lg * 4 + r;
                float bv = bias[oc];
                #pragma unroll
                for (int pt = 0; pt < 4; ++pt)
                    outf[(size_t)oc * HW_SZ + pt * 16 + l16] = acc[ob][pt][r] + bv;
            }
        }
    } else {
        float* s_ep = (float*)sbuf + wv * 1088;   // per-wave private 64px x 17
        for (int ob = 0; ob < 4; ++ob) {
            int obg = mb * 8 + ocw * 4 + ob;
            if (obg * 16 >= Cout) continue;       // wave-uniform
            #pragma unroll
            for (int r = 0; r < 4; ++r) {
                float bv = bias[obg * 16 + lg * 4 + r];
                #pragma unroll
                for (int pt = 0; pt < 4; ++pt)
                    s_ep[(pt * 16 + l16) * 17 + lg * 4 + r] = acc[ob][pt][r] + bv;
            }
            size_t pxg = (size_t)img * HW_SZ + (size_t)(y0 + yr) * 64 + lane;
            if (outmode == 1) {
                float* op = (float*)outp + pxg * Cout + obg * 16;
                #pragma unroll
                for (int jj = 0; jj < 4; ++jj) {
                    float4 t4;
                    t4.x = s_ep[lane * 17 + jj * 4 + 0];
                    t4.y = s_ep[lane * 17 + jj * 4 + 1];
                    t4.z = s_ep[lane * 17 + jj * 4 + 2];
                    t4.w = s_ep[lane * 17 + jj * 4 + 3];
                    *(float4*)(op + jj * 4) = t4;
                }
            } else {
                unsigned short* op = (unsigned short*)outp + pxg * Cout + obg * 16;
                unsigned v[8];
                #pragma unroll
                for (int j = 0; j < 8; ++j) {
                    unsigned lo = f2bf(s_ep[lane * 17 + 2 * j]);
                    unsigned hi = f2bf(s_ep[lane * 17 + 2 * j + 1]);
                    v[j] = lo | (hi << 16);
                }
                uint4 o0; o0.x = v[0]; o0.y = v[1]; o0.z = v[2]; o0.w = v[3];
                uint4 o1; o1.x = v[4]; o1.y = v[5]; o1.z = v[6]; o1.w = v[7];
                *(uint4*)(op) = o0;
                *(uint4*)(op + 8) = o1;
            }
        }
    }
}

// merged / standalone value+qconv launch. grid (32, nY). g = ybase + blockIdx.y:
//   g in [0,12): value conv  img=g>>1, mb=g&1   (256->256, out bf16 pm)
//   g in [12,18): qconv      img=(g-12)/3, mb=(g-12)%3 (768->288, out f32 pm)
__global__ __launch_bounds__(256) void conv_main(
    int ybase,
    const unsigned short* __restrict__ vin, const unsigned short* __restrict__ wv_,
    const float* __restrict__ bv, unsigned short* __restrict__ vout,
    const unsigned short* __restrict__ qin, const unsigned short* __restrict__ wq_,
    const float* __restrict__ bq, float* __restrict__ qout,
    const unsigned short* __restrict__ zbuf)
{
    __shared__ __align__(16) unsigned short sbuf[2 * 8448];
    int g = ybase + blockIdx.y;
    int y0 = blockIdx.x * 2;
    if (g < 12) {
        int img = g >> 1, mb = g & 1;
        conv_core(vin + (size_t)img * HW_SZ * 256, wv_, bv, zbuf, (void*)vout,
                  256, 8, 16, 256, mb, y0, 0, img, sbuf);
    } else {
        int h = g - 12; int img = h / 3, mb = h - img * 3;
        conv_core(qin + (size_t)img * HW_SZ * 768, wq_, bq, zbuf, (void*)qout,
                  768, 24, 24, 288, mb, y0, 1, img, sbuf);
    }
}

// out conv: grid (32, 2, 2) = (rowpair, mb, img). NCHW f32 -> d_out.
__global__ __launch_bounds__(256) void conv_out_k(
    const unsigned short* __restrict__ din, const unsigned short* __restrict__ wo_,
    const float* __restrict__ bo, float* __restrict__ outp,
    const unsigned short* __restrict__ zbuf)
{
    __shared__ __align__(16) unsigned short sbuf[2 * 8448];
    conv_core(din + (size_t)blockIdx.z * HW_SZ * 256, wo_, bo, zbuf, (void*)outp,
              256, 8, 16, 256, blockIdx.y, blockIdx.x * 2, 2, blockIdx.z, sbuf);
}

// ---------------- deform sampling ----------------
__global__ __launch_bounds__(256) void deform_kernel(
    const unsigned short* __restrict__ value_bf,
    const float* __restrict__ qout,
    const float* __restrict__ refp,
    const float* __restrict__ flow_fwd,
    const float* __restrict__ flow_bwd,
    unsigned short* __restrict__ dout)
{
    int gid = blockIdx.x * 256 + threadIdx.x;
    int d = gid & 31;
    int m = (gid >> 5) & 7;
    int q = (gid >> 8) & 4095;
    int b = gid >> 20;

    const float* qbase = qout + ((size_t)b * HW_SZ + q) * 288;
    const float* al = qbase + 192 + m * 12;
    float lg[12];
    float mx = -1e30f;
    #pragma unroll
    for (int i = 0; i < 12; i++) { lg[i] = al[i]; mx = fmaxf(mx, lg[i]); }
    float s = 0.f;
    #pragma unroll
    for (int i = 0; i < 12; i++) { lg[i] = __expf(lg[i] - mx); s += lg[i]; }
    float inv = 1.f / s;

    const float* op = qbase + m * 24;
    const float* rp = refp + ((size_t)b * HW_SZ + q) * 6;

    float acc = 0.f;
    #pragma unroll
    for (int t = 0; t < 3; t++) {
        float fx = 0.f, fy = 0.f;
        if (t == 0) {
            fx = flow_bwd[((b * 2 + 0) * 2 + 0) * HW_SZ + q];
            fy = flow_bwd[((b * 2 + 0) * 2 + 1) * HW_SZ + q];
        } else if (t == 2) {
            fx = flow_fwd[((b * 2 + 1) * 2 + 0) * HW_SZ + q];
            fy = flow_fwd[((b * 2 + 1) * 2 + 1) * HW_SZ + q];
        }
        float rx = rp[t * 2 + 0], ry = rp[t * 2 + 1];
        const unsigned short* vbase = value_bf + (size_t)(b * 3 + t) * (HW_SZ * 256) + m * 32 + d;
        #pragma unroll
        for (int pp = 0; pp < 4; pp++) {
            float ox = op[t * 8 + pp * 2 + 0] + fx;
            float oy = op[t * 8 + pp * 2 + 1] + fy;
            float aw = lg[t * 4 + pp] * inv;
            float x = rx * 64.f + ox - 0.5f;
            float y = ry * 64.f + oy - 0.5f;
            float x0f = floorf(x), y0f = floorf(y);
            float wx = x - x0f, wy = y - y0f;
            int x0 = (int)x0f, y0 = (int)y0f;
            int x1 = x0 + 1, y1 = y0 + 1;
            bool vx0 = (x0 >= 0) & (x0 < 64), vx1 = (x1 >= 0) & (x1 < 64);
            bool vy0 = (y0 >= 0) & (y0 < 64), vy1 = (y1 >= 0) & (y1 < 64);
            int cx0 = min(max(x0, 0), 63), cx1 = min(max(x1, 0), 63);
            int cy0 = min(max(y0, 0), 63), cy1 = min(max(y1, 0), 63);
            float w00 = (1.f - wx) * (1.f - wy) * ((vx0 & vy0) ? 1.f : 0.f);
            float w10 = wx * (1.f - wy) * ((vx1 & vy0) ? 1.f : 0.f);
            float w01 = (1.f - wx) * wy * ((vx0 & vy1) ? 1.f : 0.f);
            float w11 = wx * wy * ((vx1 & vy1) ? 1.f : 0.f);
            float v00 = bf2f(vbase[(cy0 * 64 + cx0) * 256]);
            float v10 = bf2f(vbase[(cy0 * 64 + cx1) * 256]);
            float v01 = bf2f(vbase[(cy1 * 64 + cx0) * 256]);
            float v11 = bf2f(vbase[(cy1 * 64 + cx1) * 256]);
            acc += aw * (w00 * v00 + w10 * v10 + w01 * v01 + w11 * v11);
        }
    }
    dout[((size_t)b * HW_SZ + q) * 256 + m * 32 + d] = f2bf(acc);
}

extern "C" void kernel_launch(void* const* d_in, const int* in_sizes, int n_in,
                              void* d_out, int out_size, void* d_ws, size_t ws_size,
                              hipStream_t stream) {
    const float* query   = (const float*)d_in[0];
    const float* refp    = (const float*)d_in[1];
    const float* inflat  = (const float*)d_in[2];
    const float* flowf   = (const float*)d_in[6];
    const float* flowb   = (const float*)d_in[7];
    const float* w_value = (const float*)d_in[8];
    const float* b_value = (const float*)d_in[9];
    const float* w_off   = (const float*)d_in[10];
    const float* b_off   = (const float*)d_in[11];
    const float* w_attn  = (const float*)d_in[12];
    const float* b_attn  = (const float*)d_in[13];
    const float* w_out   = (const float*)d_in[14];
    const float* b_out   = (const float*)d_in[15];

    char* ws = (char*)d_ws;
    // common regions
    unsigned short* wpk_v    = (unsigned short*)(ws);                    // 1,179,648
    unsigned short* wpk_q    = (unsigned short*)(ws + 1179648);          // 5,308,416
    unsigned short* wpk_o    = (unsigned short*)(ws + 6488064);          // 1,179,648
    float*          qbias    = (float*)(ws + 7667712);                   // 1,536
    float*          zbuf     = (float*)(ws + 7669248);                   // 64
    unsigned short* value_bf = (unsigned short*)(ws + 7669760);          // 12,582,912
    unsigned short* qin_bf   = (unsigned short*)(ws + 20252672);         // 12,582,912
    unsigned short* vin_bf   = (unsigned short*)(ws + 32835584);         // 12,582,912

    const bool big = ws_size >= 54855680ull;
    // big:    qout @45,418,496 (own region); dout over wpk_q (dead after conv_main)
    // small:  qout over vin_bf (dead after value conv); dout @42,272,768 (R2 layout)
    float*          qout    = big ? (float*)(ws + 45418496)
                                  : (float*)(ws + 32835584);
    unsigned short* dout_bf = big ? (unsigned short*)(ws + 1179648)
                                  : (unsigned short*)(ws + 32835584 + 9437184);

    // 1) weight repack + biases + zero stub
    repack_w<<<dim3(288), dim3(256), 0, stream>>>(w_value, w_value, 256, 256, 256, 16, wpk_v, 73728);
    repack_w<<<dim3(1296), dim3(256), 0, stream>>>(w_off, w_attn, 192, 288, 768, 24, wpk_q, 331776);
    repack_w<<<dim3(288), dim3(256), 0, stream>>>(w_out, w_out, 256, 256, 256, 16, wpk_o, 73728);
    build_qbias<<<dim3(3), dim3(128), 0, stream>>>(b_off, b_attn, qbias, zbuf);

    // 2) transpose inputs to pixel-major bf16
    nchw_to_pm<<<dim3(64, 8, 6), dim3(256), 0, stream>>>(inflat, vin_bf, 256);
    nchw_to_pm<<<dim3(64, 24, 2), dim3(256), 0, stream>>>(query, qin_bf, 768);

    // 3) convs
    if (big) {
        conv_main<<<dim3(32, 18), dim3(256), 0, stream>>>(
            0, vin_bf, wpk_v, b_value, value_bf, qin_bf, wpk_q, qbias, qout,
            (const unsigned short*)zbuf);
    } else {
        conv_main<<<dim3(32, 12), dim3(256), 0, stream>>>(
            0, vin_bf, wpk_v, b_value, value_bf, qin_bf, wpk_q, qbias, qout,
            (const unsigned short*)zbuf);
        conv_main<<<dim3(32, 6), dim3(256), 0, stream>>>(
            12, vin_bf, wpk_v, b_value, value_bf, qin_bf, wpk_q, qbias, qout,
            (const unsigned short*)zbuf);
    }

    // 4) deform sampling
    deform_kernel<<<dim3(8192), dim3(256), 0, stream>>>(
        value_bf, qout, refp, flowf, flowb, dout_bf);

    // 5) output conv -> d_out (NCHW f32)
    conv_out_k<<<dim3(32, 2, 2), dim3(256), 0, stream>>>(
        dout_bf, wpk_o, b_out, (float*)d_out, (const unsigned short*)zbuf);
}

// Round 4
// 380.619 us; speedup vs baseline: 6.9894x; 1.0967x over previous
//
#include <hip/hip_runtime.h>

// MSDeformAttn fusion, MI355X. Round 4: 2-wave/1-row conv blocks,
// rolling 3-tap weight-fragment register prefetch, fused prep/transpose.
// B=2, T=3, C=256, H=W=64, M=8, P=4, DH=32.

#define HW_SZ 4096

typedef __attribute__((ext_vector_type(8))) short short8;
typedef __attribute__((ext_vector_type(4))) float f32x4;

__device__ __forceinline__ unsigned short f2bf(float f) {
    union { float f; unsigned u; } v; v.f = f;
    unsigned u = v.u;
    unsigned r = (u + 0x7FFFu + ((u >> 16) & 1u)) >> 16;
    return (unsigned short)r;
}
__device__ __forceinline__ float bf2f(unsigned short h) {
    union { unsigned u; float f; } v; v.u = ((unsigned)h) << 16;
    return v.f;
}

__device__ __forceinline__ void gld16(const void* g, void* l) {
    __builtin_amdgcn_global_load_lds(
        (const __attribute__((address_space(1))) unsigned*)g,
        (__attribute__((address_space(3))) unsigned*)l, 16, 0, 0);
}

// ---------------- fused prep: 3 weight repacks + qbias + zbuf ----------------
__device__ __forceinline__ void repack_one(
    int g, const float* __restrict__ w0, const float* __restrict__ w1,
    int split, int Cout, int Cin, int OBp, unsigned short* __restrict__ out)
{
    int lane = g & 63;
    int rest = g >> 6;
    int KB = Cin >> 5;
    int kb = rest % KB; int rest2 = rest / KB;
    int ob = rest2 % OBp; int tap = rest2 / OBp;
    int oc = ob * 16 + (lane & 15);
    int ic0 = kb * 32 + (lane >> 4) * 8;
    unsigned v[4];
    #pragma unroll
    for (int j = 0; j < 4; ++j) {
        unsigned lo = 0, hi = 0;
        int ic = ic0 + 2 * j;
        if (oc < split) {
            lo = f2bf(w0[((size_t)oc * Cin + ic) * 9 + tap]);
            hi = f2bf(w0[((size_t)oc * Cin + ic + 1) * 9 + tap]);
        } else if (oc < Cout) {
            lo = f2bf(w1[((size_t)(oc - split) * Cin + ic) * 9 + tap]);
            hi = f2bf(w1[((size_t)(oc - split) * Cin + ic + 1) * 9 + tap]);
        }
        v[j] = lo | (hi << 16);
    }
    uint4 o; o.x = v[0]; o.y = v[1]; o.z = v[2]; o.w = v[3];
    *(uint4*)(out + (size_t)g * 8) = o;
}

__global__ __launch_bounds__(256) void prep_all(
    const float* __restrict__ w_value, const float* __restrict__ w_off,
    const float* __restrict__ w_attn, const float* __restrict__ w_out,
    const float* __restrict__ b_off, const float* __restrict__ b_attn,
    unsigned short* __restrict__ wpk_v, unsigned short* __restrict__ wpk_q,
    unsigned short* __restrict__ wpk_o, float* __restrict__ qbias,
    float* __restrict__ zbuf)
{
    int g = blockIdx.x * 256 + threadIdx.x;
    if (g < 73728) {
        repack_one(g, w_value, w_value, 256, 256, 256, 16, wpk_v);
    } else if (g < 405504) {
        repack_one(g - 73728, w_off, w_attn, 192, 288, 768, 24, wpk_q);
    } else if (g < 479232) {
        repack_one(g - 405504, w_out, w_out, 256, 256, 256, 16, wpk_o);
    } else {
        int i = g - 479232;
        if (i < 16) zbuf[i] = 0.f;
        if (i < 384) {
            float v = 0.f;
            if (i < 192) v = b_off[i]; else if (i < 288) v = b_attn[i - 192];
            qbias[i] = v;
        }
    }
}

// ---------------- fused NCHW fp32 -> pixel-major bf16 transpose ----------------
// grid (64, 96): z<48 value (img=z/8, kb=z%8, Cin=256); else query (Cin=768)
__global__ __launch_bounds__(256) void nchw_to_pm2(
    const float* __restrict__ vin_src, const float* __restrict__ qin_src,
    unsigned short* __restrict__ vdst, unsigned short* __restrict__ qdst)
{
    int y = blockIdx.x, z = blockIdx.y;
    const float* in; unsigned short* out; int Cin, img, kb;
    if (z < 48) { img = z >> 3; kb = z & 7; in = vin_src; out = vdst; Cin = 256; }
    else { int h = z - 48; img = h / 24; kb = h % 24; in = qin_src; out = qdst; Cin = 768; }

    __shared__ float s[32][65];
    int t = threadIdx.x;
    int x = t & 63, ic4 = t >> 6;
    const float* ip = in + ((size_t)img * Cin + kb * 32) * HW_SZ + y * 64;
    #pragma unroll
    for (int i = 0; i < 8; ++i) {
        int icl = ic4 * 8 + i;
        s[icl][x] = ip[(size_t)icl * HW_SZ + x];
    }
    __syncthreads();
    int p = t >> 2, h4 = t & 3;
    unsigned v[4];
    #pragma unroll
    for (int j = 0; j < 4; ++j) {
        unsigned lo = f2bf(s[h4 * 8 + 2 * j][p]);
        unsigned hi = f2bf(s[h4 * 8 + 2 * j + 1][p]);
        v[j] = lo | (hi << 16);
    }
    uint4 o; o.x = v[0]; o.y = v[1]; o.z = v[2]; o.w = v[3];
    *(uint4*)(out + ((size_t)img * HW_SZ + y * 64 + p) * Cin + kb * 32 + h4 * 8) = o;
}

// ---------------- pipelined MFMA conv core (2 waves, 1 output row) ----------------
// Block: 128 thr = 2 waves; wave wv = oc half. Tile: 128 oc x 64 px (row y0).
// LDS: 2 buffers x [3 rows][4 icg][66 cols] 16B units = 2 x 12672 B.
// Weight frags: rolling 3-tap register prefetch (afr[3][4]).
__device__ __forceinline__ void conv_core(
    const unsigned short* __restrict__ gin,
    const unsigned short* __restrict__ wpk,   // [9][OBp][KB][64][8]
    const float* __restrict__ bias,
    const unsigned short* __restrict__ zbuf,
    void* __restrict__ outp,
    int Cin, int KB, int OBp, int Cout, int mb, int y0, int outmode, int img,
    unsigned short* sbuf)
{
    const int tid = threadIdx.x;
    const int wv = tid >> 6, lane = tid & 63;
    const int l16 = lane & 15, lg = lane >> 4;
    const int obBase = mb * 8 + wv * 4;

    // precompute staging sources; wave wv takes issues ii = 2i+wv (13 total)
    const unsigned short* sptr[7];
    int okk[7];
    #pragma unroll
    for (int i = 0; i < 7; ++i) {
        int ii = 2 * i + wv;
        int r = ii * 64 + lane;
        sptr[i] = zbuf; okk[i] = 0;
        if (ii < 13 && r < 792) {
            int rr = r / 264;
            int rem = r - rr * 264;
            int icg = rem / 66;
            int cc = rem - icg * 66;
            int gy = y0 - 1 + rr, gx = cc - 1;
            if ((unsigned)gy < 64u && (unsigned)gx < 64u) {
                sptr[i] = gin + ((size_t)(gy * 64 + gx)) * Cin + icg * 8;
                okk[i] = 1;
            }
        }
    }

    f32x4 acc[4][4];
    #pragma unroll
    for (int a = 0; a < 4; ++a)
        #pragma unroll
        for (int b = 0; b < 4; ++b)
            acc[a][b] = (f32x4){0.f, 0.f, 0.f, 0.f};

    auto stage = [&](int kb, unsigned short* sb) {
        #pragma unroll
        for (int i = 0; i < 7; ++i) {
            int ii = 2 * i + wv;
            int r = ii * 64 + lane;
            if (ii < 13 && r < 792) {
                const unsigned short* s = sptr[i] + (okk[i] ? (size_t)kb * 32 : 0);
                gld16(s, sb + (size_t)ii * 64 * 8);
            }
        }
    };

    short8 afr[3][4];
    auto ldA = [&](int kb, int tap, int slot) {
        const unsigned short* wp =
            wpk + (((size_t)tap * OBp + obBase) * KB + kb) * 512;
        #pragma unroll
        for (int ob = 0; ob < 4; ++ob)
            afr[slot][ob] = *(const short8*)(wp + (size_t)ob * KB * 512 + lane * 8);
    };

    stage(0, sbuf);
    for (int kb = 0; kb < KB; ++kb) {
        __syncthreads();                       // buffer kb ready (drains vmcnt)
        if (kb + 1 < KB) stage(kb + 1, sbuf + ((kb + 1) & 1) * 6336);
        ldA(kb, 0, 0); ldA(kb, 1, 1); ldA(kb, 2, 2);
        const unsigned short* cb = sbuf + (kb & 1) * 6336;
        #pragma unroll
        for (int tap = 0; tap < 9; ++tap) {
            const int ky = tap / 3, kx = tap % 3;
            const int slot = tap % 3;
            short8 bfr[4];
            #pragma unroll
            for (int pt = 0; pt < 4; ++pt)
                bfr[pt] = *(const short8*)(cb + (ky * 264 + lg * 66 + kx + pt * 16 + l16) * 8);
            #pragma unroll
            for (int ob = 0; ob < 4; ++ob)
                #pragma unroll
                for (int pt = 0; pt < 4; ++pt)
                    acc[ob][pt] = __builtin_amdgcn_mfma_f32_16x16x32_bf16(
                        afr[slot][ob], bfr[pt], acc[ob][pt], 0, 0, 0);
            if (tap < 6) ldA(kb, tap + 3, slot);
        }
    }

    if (outmode == 2) {
        float* outf = (float*)outp + (size_t)img * Cout * HW_SZ + (size_t)y0 * 64;
        #pragma unroll
        for (int ob = 0; ob < 4; ++ob) {
            int obg = obBase + ob;
            #pragma unroll
            for (int r = 0; r < 4; ++r) {
                int oc = obg * 16 + lg * 4 + r;
                float bv = bias[oc];
                #pragma unroll
                for (int pt = 0; pt < 4; ++pt)
                    outf[(size_t)oc * HW_SZ + pt * 16 + l16] = acc[ob][pt][r] + bv;
            }
        }
    } else {
        __syncthreads();                       // LDS reads done; reuse for epilogue
        float* s_ep = (float*)sbuf + wv * 1088;  // per-wave 64px x 17
        for (int ob = 0; ob < 4; ++ob) {
            int obg = obBase + ob;
            if (obg * 16 >= Cout) continue;    // wave-uniform
            #pragma unroll
            for (int r = 0; r < 4; ++r) {
                float bv = bias[obg * 16 + lg * 4 + r];
                #pragma unroll
                for (int pt = 0; pt < 4; ++pt)
                    s_ep[(pt * 16 + l16) * 17 + lg * 4 + r] = acc[ob][pt][r] + bv;
            }
            size_t pxg = (size_t)img * HW_SZ + (size_t)y0 * 64 + lane;
            if (outmode == 1) {
                float* op = (float*)outp + pxg * Cout + obg * 16;
                #pragma unroll
                for (int jj = 0; jj < 4; ++jj) {
                    float4 t4;
                    t4.x = s_ep[lane * 17 + jj * 4 + 0];
                    t4.y = s_ep[lane * 17 + jj * 4 + 1];
                    t4.z = s_ep[lane * 17 + jj * 4 + 2];
                    t4.w = s_ep[lane * 17 + jj * 4 + 3];
                    *(float4*)(op + jj * 4) = t4;
                }
            } else {
                unsigned short* op = (unsigned short*)outp + pxg * Cout + obg * 16;
                unsigned v[8];
                #pragma unroll
                for (int j = 0; j < 8; ++j) {
                    unsigned lo = f2bf(s_ep[lane * 17 + 2 * j]);
                    unsigned hi = f2bf(s_ep[lane * 17 + 2 * j + 1]);
                    v[j] = lo | (hi << 16);
                }
                uint4 o0; o0.x = v[0]; o0.y = v[1]; o0.z = v[2]; o0.w = v[3];
                uint4 o1; o1.x = v[4]; o1.y = v[5]; o1.z = v[6]; o1.w = v[7];
                *(uint4*)(op) = o0;
                *(uint4*)(op + 8) = o1;
            }
        }
    }
}

// merged value+qconv. g = ybase + blockIdx.y:
//   g in [0,6):  qconv  img=g/3, mb=g%3  (768->288, f32 pm)  -- heavy, first
//   g in [6,18): value  img=(g-6)>>1, mb=(g-6)&1 (256->256, bf16 pm)
__global__ __launch_bounds__(128, 2) void conv_main(
    int ybase,
    const unsigned short* __restrict__ vin, const unsigned short* __restrict__ wv_,
    const float* __restrict__ bv, unsigned short* __restrict__ vout,
    const unsigned short* __restrict__ qin, const unsigned short* __restrict__ wq_,
    const float* __restrict__ bq, float* __restrict__ qout,
    const unsigned short* __restrict__ zbuf)
{
    __shared__ __align__(16) unsigned short sbuf[2 * 6336];
    int g = ybase + blockIdx.y;
    int y0 = blockIdx.x;
    if (g < 6) {
        int img = g / 3, mb = g - img * 3;
        conv_core(qin + (size_t)img * HW_SZ * 768, wq_, bq, zbuf, (void*)qout,
                  768, 24, 24, 288, mb, y0, 1, img, sbuf);
    } else {
        int h = g - 6; int img = h >> 1, mb = h & 1;
        conv_core(vin + (size_t)img * HW_SZ * 256, wv_, bv, zbuf, (void*)vout,
                  256, 8, 16, 256, mb, y0, 0, img, sbuf);
    }
}

// out conv: grid (64, 4) = (row, img*2+mb). NCHW f32 -> d_out.
__global__ __launch_bounds__(128, 2) void conv_out_k(
    const unsigned short* __restrict__ din, const unsigned short* __restrict__ wo_,
    const float* __restrict__ bo, float* __restrict__ outp,
    const unsigned short* __restrict__ zbuf)
{
    __shared__ __align__(16) unsigned short sbuf[2 * 6336];
    int img = blockIdx.y >> 1, mb = blockIdx.y & 1;
    conv_core(din + (size_t)img * HW_SZ * 256, wo_, bo, zbuf, (void*)outp,
              256, 8, 16, 256, mb, blockIdx.x, 2, img, sbuf);
}

// ---------------- deform sampling ----------------
__global__ __launch_bounds__(256) void deform_kernel(
    const unsigned short* __restrict__ value_bf,
    const float* __restrict__ qout,
    const float* __restrict__ refp,
    const float* __restrict__ flow_fwd,
    const float* __restrict__ flow_bwd,
    unsigned short* __restrict__ dout)
{
    int gid = blockIdx.x * 256 + threadIdx.x;
    int d = gid & 31;
    int m = (gid >> 5) & 7;
    int q = (gid >> 8) & 4095;
    int b = gid >> 20;

    const float* qbase = qout + ((size_t)b * HW_SZ + q) * 288;
    const float* al = qbase + 192 + m * 12;
    float lg[12];
    float mx = -1e30f;
    #pragma unroll
    for (int i = 0; i < 12; i++) { lg[i] = al[i]; mx = fmaxf(mx, lg[i]); }
    float s = 0.f;
    #pragma unroll
    for (int i = 0; i < 12; i++) { lg[i] = __expf(lg[i] - mx); s += lg[i]; }
    float inv = 1.f / s;

    const float* op = qbase + m * 24;
    const float* rp = refp + ((size_t)b * HW_SZ + q) * 6;

    float acc = 0.f;
    #pragma unroll
    for (int t = 0; t < 3; t++) {
        float fx = 0.f, fy = 0.f;
        if (t == 0) {
            fx = flow_bwd[((b * 2 + 0) * 2 + 0) * HW_SZ + q];
            fy = flow_bwd[((b * 2 + 0) * 2 + 1) * HW_SZ + q];
        } else if (t == 2) {
            fx = flow_fwd[((b * 2 + 1) * 2 + 0) * HW_SZ + q];
            fy = flow_fwd[((b * 2 + 1) * 2 + 1) * HW_SZ + q];
        }
        float rx = rp[t * 2 + 0], ry = rp[t * 2 + 1];
        const unsigned short* vbase = value_bf + (size_t)(b * 3 + t) * (HW_SZ * 256) + m * 32 + d;
        #pragma unroll
        for (int pp = 0; pp < 4; pp++) {
            float ox = op[t * 8 + pp * 2 + 0] + fx;
            float oy = op[t * 8 + pp * 2 + 1] + fy;
            float aw = lg[t * 4 + pp] * inv;
            float x = rx * 64.f + ox - 0.5f;
            float y = ry * 64.f + oy - 0.5f;
            float x0f = floorf(x), y0f = floorf(y);
            float wx = x - x0f, wy = y - y0f;
            int x0 = (int)x0f, y0 = (int)y0f;
            int x1 = x0 + 1, y1 = y0 + 1;
            bool vx0 = (x0 >= 0) & (x0 < 64), vx1 = (x1 >= 0) & (x1 < 64);
            bool vy0 = (y0 >= 0) & (y0 < 64), vy1 = (y1 >= 0) & (y1 < 64);
            int cx0 = min(max(x0, 0), 63), cx1 = min(max(x1, 0), 63);
            int cy0 = min(max(y0, 0), 63), cy1 = min(max(y1, 0), 63);
            float w00 = (1.f - wx) * (1.f - wy) * ((vx0 & vy0) ? 1.f : 0.f);
            float w10 = wx * (1.f - wy) * ((vx1 & vy0) ? 1.f : 0.f);
            float w01 = (1.f - wx) * wy * ((vx0 & vy1) ? 1.f : 0.f);
            float w11 = wx * wy * ((vx1 & vy1) ? 1.f : 0.f);
            float v00 = bf2f(vbase[(cy0 * 64 + cx0) * 256]);
            float v10 = bf2f(vbase[(cy0 * 64 + cx1) * 256]);
            float v01 = bf2f(vbase[(cy1 * 64 + cx0) * 256]);
            float v11 = bf2f(vbase[(cy1 * 64 + cx1) * 256]);
            acc += aw * (w00 * v00 + w10 * v10 + w01 * v01 + w11 * v11);
        }
    }
    dout[((size_t)b * HW_SZ + q) * 256 + m * 32 + d] = f2bf(acc);
}

extern "C" void kernel_launch(void* const* d_in, const int* in_sizes, int n_in,
                              void* d_out, int out_size, void* d_ws, size_t ws_size,
                              hipStream_t stream) {
    const float* query   = (const float*)d_in[0];
    const float* refp    = (const float*)d_in[1];
    const float* inflat  = (const float*)d_in[2];
    const float* flowf   = (const float*)d_in[6];
    const float* flowb   = (const float*)d_in[7];
    const float* w_value = (const float*)d_in[8];
    const float* b_value = (const float*)d_in[9];
    const float* w_off   = (const float*)d_in[10];
    const float* b_off   = (const float*)d_in[11];
    const float* w_attn  = (const float*)d_in[12];
    const float* b_attn  = (const float*)d_in[13];
    const float* w_out   = (const float*)d_in[14];
    const float* b_out   = (const float*)d_in[15];

    char* ws = (char*)d_ws;
    unsigned short* wpk_v    = (unsigned short*)(ws);                    // 1,179,648
    unsigned short* wpk_q    = (unsigned short*)(ws + 1179648);          // 5,308,416
    unsigned short* wpk_o    = (unsigned short*)(ws + 6488064);          // 1,179,648
    float*          qbias    = (float*)(ws + 7667712);                   // 1,536
    float*          zbuf     = (float*)(ws + 7669248);                   // 64
    unsigned short* value_bf = (unsigned short*)(ws + 7669760);          // 12,582,912
    unsigned short* qin_bf   = (unsigned short*)(ws + 20252672);         // 12,582,912
    unsigned short* vin_bf   = (unsigned short*)(ws + 32835584);         // 12,582,912

    const bool big = ws_size >= 54855680ull;
    float*          qout    = big ? (float*)(ws + 45418496)
                                  : (float*)(ws + 32835584);
    unsigned short* dout_bf = big ? (unsigned short*)(ws + 1179648)
                                  : (unsigned short*)(ws + 32835584 + 9437184);

    // 1) fused weight repack + biases + zero stub
    prep_all<<<dim3(1874), dim3(256), 0, stream>>>(
        w_value, w_off, w_attn, w_out, b_off, b_attn,
        wpk_v, wpk_q, wpk_o, qbias, zbuf);

    // 2) fused transpose of both inputs to pixel-major bf16
    nchw_to_pm2<<<dim3(64, 96), dim3(256), 0, stream>>>(
        inflat, query, vin_bf, qin_bf);

    // 3) convs (q-groups first for tail balance)
    if (big) {
        conv_main<<<dim3(64, 18), dim3(128), 0, stream>>>(
            0, vin_bf, wpk_v, b_value, value_bf, qin_bf, wpk_q, qbias, qout,
            (const unsigned short*)zbuf);
    } else {
        // small ws: qout aliases vin_bf -> run value conv first, then qconv
        conv_main<<<dim3(64, 12), dim3(128), 0, stream>>>(
            6, vin_bf, wpk_v, b_value, value_bf, qin_bf, wpk_q, qbias, qout,
            (const unsigned short*)zbuf);
        conv_main<<<dim3(64, 6), dim3(128), 0, stream>>>(
            0, vin_bf, wpk_v, b_value, value_bf, qin_bf, wpk_q, qbias, qout,
            (const unsigned short*)zbuf);
    }

    // 4) deform sampling
    deform_kernel<<<dim3(8192), dim3(256), 0, stream>>>(
        value_bf, qout, refp, flowf, flowb, dout_bf);

    // 5) output conv -> d_out (NCHW f32)
    conv_out_k<<<dim3(64, 4), dim3(128), 0, stream>>>(
        dout_bf, wpk_o, b_out, (float*)d_out, (const unsigned short*)zbuf);
}